// Round 6
// baseline (38.964 us; speedup 1.0000x reference)
//
#include <hip/hip_runtime.h>
#include <stdint.h>

#define NB    4
#define NL0   2048
#define NL1   2048
#define NC    64
#define KMAX  128
#define CAP   192
#define NSLOT 3
#define NG1   9
#define NBINS 729
#define FLOWN (NB*NL0*3)
#define QPB   8
#define TPB   512

__global__ __launch_bounds__(TPB, 8) void fine_match_kernel(
    const float* __restrict__ x0, const float* __restrict__ x1,
    const float* __restrict__ pos0, const float* __restrict__ pos1,
    const void* __restrict__ padraw, float* __restrict__ out)
{
  __shared__ float4         s_pos[NL1];       // xyz + decoded pad in .w (32 KB)
  __shared__ float          s_x0[QPB*NC];     // 2 KB
  __shared__ float          s_p0[QPB][3];
  __shared__ unsigned short s_jj[QPB][CAP];   // 3 KB
  __shared__ float          s_corr[QPB][CAP]; // 6 KB, lane-private slots

  const int t = threadIdx.x;
  const int bid = blockIdx.x;
  const int b = bid >> 8;                 // 256 blocks per batch
  const int l0base = (bid & 255) * QPB;

  // ---- issue zero-fill of this block's flow_dist region FIRST ----
  {
    float4 z4; z4.x = z4.y = z4.z = z4.w = 0.0f;
    float4* bz = (float4*)(out + FLOWN + (size_t)(b*NL0 + l0base)*NBINS);
    for (int i = t; i < QPB*NBINS/4; i += TPB) bz[i] = z4;    // 1458 float4s
  }

  // ---- pad width detection: 4-byte (i32 / f32 bool) vs packed byte ----
  int wide;
  {
    const uint32_t* pi = (const uint32_t*)padraw;
    int ok4 = 1;
    for (int i = t; i < (NB*NL1)/4; i += TPB) {
      const uint32_t v = pi[i];
      ok4 &= (int)((v <= 1u) | (v == 0x3F800000u));
    }
    wide = __syncthreads_and(ok4);        // block-uniform
  }

  // ---- staging: pos1 xyz + decoded pad -> float4 LDS; x0 rows; pos0 ----
  {
    const float* p1b = pos1 + (size_t)b*NL1*3;
    for (int i = t; i < NL1; i += TPB) {      // 4 iterations
      float pv;
      if (wide) pv = (((const uint32_t*)padraw)[b*NL1 + i] != 0u) ? 1.0f : 0.0f;
      else      pv = (((const uint8_t*)padraw)[b*NL1 + i] != 0)   ? 1.0f : 0.0f;
      float4 p; p.x = p1b[i*3+0]; p.y = p1b[i*3+1]; p.z = p1b[i*3+2]; p.w = pv;
      s_pos[i] = p;
    }
  }
  s_x0[t] = x0[(size_t)(b*NL0 + l0base)*NC + t];              // TPB == QPB*NC
  if (t < QPB*3) {
    const int q = t/3, c = t - q*3;
    s_p0[q][c] = pos0[(b*NL0 + l0base + q)*3 + c];
  }
  __syncthreads();   // the ONLY block barrier: LDS visible + zero-stores drained

  const int wv = t >> 6, lane = t & 63;
  const int l0 = l0base + wv;
  const float p0x = s_p0[wv][0], p0y = s_p0[wv][1], p0z = s_p0[wv][2];

  // ---- phase 1: radius scan (one ds_read_b128/point) + wave compaction ----
  int cnt = 0;
  for (int base = 0; base < NL1; base += 64) {
    const int j = base + lane;
    const float4 p = s_pos[j];                 // lane-consecutive 16B: conflict-free
    const float dx = __fsub_rn(p.x, p0x);
    const float dy = __fsub_rn(p.y, p0y);
    const float dz = __fsub_rn(p.z, p0z);
    const float d2 = __fadd_rn(__fadd_rn(__fmul_rn(dx,dx), __fmul_rn(dy,dy)), __fmul_rn(dz,dz));
    const bool ok = d2 < 0.0324f;              // strict <, matches reference
    const uint64_t m = __ballot(ok);
    if (ok) {
      const int pos = cnt + (int)__popcll(m & ((1ull << lane) - 1ull));
      if (pos < CAP) s_jj[wv][pos] = (unsigned short)j;
    }
    cnt += (int)__popcll(m);
  }
  if (cnt > CAP) cnt = CAP;
  // no barrier: s_jj / s_corr are wave-private from here on

  // ---- phase 2: pad filter (.w), rare exact rank-select, correlation ----
  const bool over = (cnt > KMAX);
  for (int s = 0; s < NSLOT; ++s) {
    if (64*s >= cnt) break;                    // wave-uniform early exit
    const int i = lane + 64*s;
    if (i < cnt) {
      float c = -1e30f;
      const int j = (int)s_jj[wv][i];
      const float4 pj = s_pos[j];
      bool k = (pj.w == 0.0f);
      if (over && k) {  // rank over ALL in-radius candidates, tie-break by list order
        const float dx = __fsub_rn(pj.x, p0x);
        const float dy = __fsub_rn(pj.y, p0y);
        const float dz = __fsub_rn(pj.z, p0z);
        const float di = __fadd_rn(__fadd_rn(__fmul_rn(dx,dx), __fmul_rn(dy,dy)), __fmul_rn(dz,dz));
        int rank = 0;
        for (int m2 = 0; m2 < cnt; ++m2) {
          const float4 pm = s_pos[(int)s_jj[wv][m2]];
          const float ex = __fsub_rn(pm.x, p0x);
          const float ey = __fsub_rn(pm.y, p0y);
          const float ez = __fsub_rn(pm.z, p0z);
          const float dm = __fadd_rn(__fadd_rn(__fmul_rn(ex,ex), __fmul_rn(ey,ey)), __fmul_rn(ez,ez));
          rank += (dm < di || (dm == di && m2 < i)) ? 1 : 0;
        }
        if (rank >= KMAX) k = false;
      }
      if (k) {
        const float* xr = x1 + ((size_t)b*NL1 + j)*NC;
        float acc = 0.0f;
        #pragma unroll
        for (int cc = 0; cc < NC; cc += 4) {
          const float4 v = *(const float4*)(xr + cc);
          const float4 q = *(const float4*)(&s_x0[wv*NC + cc]);  // broadcast
          acc += q.x*v.x + q.y*v.y + q.z*v.z + q.w*v.w;
        }
        c = acc * 0.125f;   // / sqrt(64)
      }
      s_corr[wv][i] = c;
    }
  }

  // ---- phase 3: wave softmax stats (max, sum) ----
  float mx = -1e30f;
  for (int s = 0; s < NSLOT; ++s) {
    if (64*s >= cnt) break;
    const int i = lane + 64*s;
    if (i < cnt) { const float c = s_corr[wv][i]; if (c > mx) mx = c; }
  }
  for (int off = 32; off; off >>= 1) { const float o = __shfl_xor(mx, off); if (o > mx) mx = o; }
  float sum = 0.0f;
  for (int s = 0; s < NSLOT; ++s) {
    if (64*s >= cnt) break;
    const int i = lane + 64*s;
    if (i < cnt) { const float c = s_corr[wv][i]; if (c > -1e30f) sum += expf(c - mx); }
  }
  for (int off = 32; off; off >>= 1) sum += __shfl_xor(sum, off);
  const float inv = (sum > 0.0f) ? (1.0f / sum) : 0.0f;

  // ---- phase 4: flow + voxel scatter (workgroup-scope atomics into local L2) ----
  float* bins = out + FLOWN + (size_t)((size_t)b*NL0 + l0)*NBINS;
  float fx = 0.0f, fy = 0.0f, fz = 0.0f;
  for (int s = 0; s < NSLOT; ++s) {
    if (64*s >= cnt) break;
    const int i = lane + 64*s;
    if (i < cnt) {
      const float c = s_corr[wv][i];
      if (c > -1e30f) {
        const float pv = expf(c - mx) * inv;     // identical to phase-3 term * inv
        const float4 pj = s_pos[(int)s_jj[wv][i]];
        const float dx = __fsub_rn(pj.x, p0x);
        const float dy = __fsub_rn(pj.y, p0y);
        const float dz = __fsub_rn(pj.z, p0z);
        fx += pv*dx; fy += pv*dy; fz += pv*dz;
        const float cx = __fdiv_rn(__fadd_rn(dx, 0.16f), 0.04f);
        const float cy = __fdiv_rn(__fadd_rn(dy, 0.16f), 0.04f);
        const float cz = __fdiv_rn(__fadd_rn(dz, 0.16f), 0.04f);
        int vx = (int)rintf(cx); vx = vx < 0 ? 0 : (vx > 8 ? 8 : vx);
        int vy = (int)rintf(cy); vy = vy < 0 ? 0 : (vy > 8 ? 8 : vy);
        int vz = (int)rintf(cz); vz = vz < 0 ? 0 : (vz > 8 ? 8 : vz);
        __hip_atomic_fetch_add(&bins[(vx*NG1 + vy)*NG1 + vz], pv,
                               __ATOMIC_RELAXED, __HIP_MEMORY_SCOPE_WORKGROUP);
      }
    }
  }
  for (int off = 32; off; off >>= 1) {
    fx += __shfl_xor(fx, off); fy += __shfl_xor(fy, off); fz += __shfl_xor(fz, off);
  }
  if (lane == 0) {
    float* f = out + (size_t)((size_t)b*NL0 + l0)*3;
    f[0] = fx; f[1] = fy; f[2] = fz;
  }
}

extern "C" void kernel_launch(void* const* d_in, const int* in_sizes, int n_in,
                              void* d_out, int out_size, void* d_ws, size_t ws_size,
                              hipStream_t stream) {
  const float* x0   = (const float*)d_in[0];
  const float* x1   = (const float*)d_in[1];
  const float* pos0 = (const float*)d_in[2];
  const float* pos1 = (const float*)d_in[3];
  const void*  pad  = d_in[4];
  float* out = (float*)d_out;
  (void)in_sizes; (void)n_in; (void)out_size; (void)d_ws; (void)ws_size;
  hipLaunchKernelGGL(fine_match_kernel, dim3(NB*NL0/QPB), dim3(TPB), 0, stream,
                     x0, x1, pos0, pos1, pad, out);
}

// Round 7
// 34.303 us; speedup vs baseline: 1.1359x; 1.1359x over previous
//
#include <hip/hip_runtime.h>
#include <stdint.h>

#define NB    4
#define NL0   2048
#define NL1   2048
#define NC    64
#define KMAX  128
#define CAP   256
#define NG1   9
#define NBINS 729
#define FLOWN (NB*NL0*3)
#define QPB   8
#define TPB   512

__global__ __launch_bounds__(TPB, 8) void fine_match_kernel(
    const float* __restrict__ x0, const float* __restrict__ x1,
    const float* __restrict__ pos0, const float* __restrict__ pos1,
    const void* __restrict__ padraw, float* __restrict__ out)
{
  __shared__ float          s_x0[QPB*NC];     // 2 KB
  __shared__ float          s_p0[QPB][3];
  __shared__ unsigned short s_jj[QPB][CAP];   // 4 KB
  __shared__ float          s_corr[QPB][CAP]; // 8 KB, lane-private slots

  const int t = threadIdx.x;
  const int bid = blockIdx.x;
  const int b = bid >> 8;                 // 256 blocks per batch
  const int l0base = (bid & 255) * QPB;

  // ---- pad width detection: 4-byte (i32 / f32 bool) vs packed byte ----
  int wide;
  {
    const uint32_t* pi = (const uint32_t*)padraw;
    int ok4 = 1;
    for (int i = t; i < (NB*NL1)/4; i += TPB) {
      const uint32_t v = pi[i];
      ok4 &= (int)((v <= 1u) | (v == 0x3F800000u));
    }
    wide = __syncthreads_and(ok4);        // block-uniform
  }

  // ---- staging: x0 rows, pos0 only; zero this block's flow_dist region ----
  s_x0[t] = x0[(size_t)(b*NL0 + l0base)*NC + t];              // TPB == QPB*NC
  if (t < QPB*3) {
    const int q = t/3, c = t - q*3;
    s_p0[q][c] = pos0[(b*NL0 + l0base + q)*3 + c];
  }
  {
    float4 z4; z4.x = z4.y = z4.z = z4.w = 0.0f;
    float4* bz = (float4*)(out + FLOWN + (size_t)(b*NL0 + l0base)*NBINS);
    for (int i = t; i < QPB*NBINS/4; i += TPB) bz[i] = z4;    // 1458 float4s
  }
  __syncthreads();   // LDS visible + zero-stores drained before any atomics

  const int wv = t >> 6, lane = t & 63;
  const int l0 = l0base + wv;
  const float p0x = s_p0[wv][0], p0y = s_p0[wv][1], p0z = s_p0[wv][2];
  const float* pb = pos1 + (size_t)b*NL1*3;   // L2-resident (96 KB, shared by 256 blocks)

  // ---- phase 1: radius scan straight from L2 + wave compaction (ordered by j) ----
  int cnt = 0;
  for (int base = 0; base < NL1; base += 64) {
    const int j = base + lane;
    const float dx = __fsub_rn(pb[j*3+0], p0x);
    const float dy = __fsub_rn(pb[j*3+1], p0y);
    const float dz = __fsub_rn(pb[j*3+2], p0z);
    const float d2 = __fadd_rn(__fadd_rn(__fmul_rn(dx,dx), __fmul_rn(dy,dy)), __fmul_rn(dz,dz));
    const bool ok = d2 < 0.0324f;              // strict <, matches reference
    const uint64_t m = __ballot(ok);
    if (ok) {
      const int pos = cnt + (int)__popcll(m & ((1ull << lane) - 1ull));
      if (pos < CAP) s_jj[wv][pos] = (unsigned short)j;
    }
    cnt += (int)__popcll(m);
  }
  if (cnt > CAP) cnt = CAP;
  __syncthreads();   // kept: mirrors round-4 structure

  // ---- phase 2: pad filter, rare exact rank-select, correlation ----
  const bool over = (cnt > KMAX);
  for (int s = 0; s < 4; ++s) {
    if (64*s >= cnt) break;                    // wave-uniform early exit
    const int i = lane + 64*s;
    if (i < cnt) {
      float c = -1e30f;
      const int j = (int)s_jj[wv][i];
      bool k;
      if (wide) k = (((const uint32_t*)padraw)[b*NL1 + j] == 0u);   // i32 / f32(0,1.0) identical
      else      k = (((const uint8_t*)padraw)[b*NL1 + j] == 0);
      if (over && k) {  // rank over ALL in-radius candidates, tie-break by list order
        const float dx = __fsub_rn(pb[j*3+0], p0x);
        const float dy = __fsub_rn(pb[j*3+1], p0y);
        const float dz = __fsub_rn(pb[j*3+2], p0z);
        const float di = __fadd_rn(__fadd_rn(__fmul_rn(dx,dx), __fmul_rn(dy,dy)), __fmul_rn(dz,dz));
        int rank = 0;
        for (int m2 = 0; m2 < cnt; ++m2) {
          const int jm = (int)s_jj[wv][m2];
          const float ex = __fsub_rn(pb[jm*3+0], p0x);
          const float ey = __fsub_rn(pb[jm*3+1], p0y);
          const float ez = __fsub_rn(pb[jm*3+2], p0z);
          const float dm = __fadd_rn(__fadd_rn(__fmul_rn(ex,ex), __fmul_rn(ey,ey)), __fmul_rn(ez,ez));
          rank += (dm < di || (dm == di && m2 < i)) ? 1 : 0;
        }
        if (rank >= KMAX) k = false;
      }
      if (k) {
        const float* xr = x1 + ((size_t)b*NL1 + j)*NC;
        float acc = 0.0f;
        #pragma unroll
        for (int cc = 0; cc < NC; cc += 4) {
          const float4 v = *(const float4*)(xr + cc);
          const float4 q = *(const float4*)(&s_x0[wv*NC + cc]);  // broadcast
          acc += q.x*v.x + q.y*v.y + q.z*v.z + q.w*v.w;
        }
        c = acc * 0.125f;   // / sqrt(64)
      }
      s_corr[wv][i] = c;
    }
  }

  // ---- phase 3: wave softmax stats (max, sum) ----
  float mx = -1e30f;
  for (int s = 0; s < 4; ++s) {
    if (64*s >= cnt) break;
    const int i = lane + 64*s;
    if (i < cnt) { const float c = s_corr[wv][i]; if (c > mx) mx = c; }
  }
  for (int off = 32; off; off >>= 1) { const float o = __shfl_xor(mx, off); if (o > mx) mx = o; }
  float sum = 0.0f;
  for (int s = 0; s < 4; ++s) {
    if (64*s >= cnt) break;
    const int i = lane + 64*s;
    if (i < cnt) { const float c = s_corr[wv][i]; if (c > -1e30f) sum += expf(c - mx); }
  }
  for (int off = 32; off; off >>= 1) sum += __shfl_xor(sum, off);
  const float inv = (sum > 0.0f) ? (1.0f / sum) : 0.0f;

  // ---- phase 4: flow + voxel scatter (workgroup-scope atomics into local L2) ----
  float* bins = out + FLOWN + (size_t)((size_t)b*NL0 + l0)*NBINS;
  float fx = 0.0f, fy = 0.0f, fz = 0.0f;
  for (int s = 0; s < 4; ++s) {
    if (64*s >= cnt) break;
    const int i = lane + 64*s;
    if (i < cnt) {
      const float c = s_corr[wv][i];
      if (c > -1e30f) {
        const float pv = expf(c - mx) * inv;     // identical to phase-3 term * inv
        const int j = (int)s_jj[wv][i];
        const float dx = __fsub_rn(pb[j*3+0], p0x);
        const float dy = __fsub_rn(pb[j*3+1], p0y);
        const float dz = __fsub_rn(pb[j*3+2], p0z);
        fx += pv*dx; fy += pv*dy; fz += pv*dz;
        const float cx = __fdiv_rn(__fadd_rn(dx, 0.16f), 0.04f);
        const float cy = __fdiv_rn(__fadd_rn(dy, 0.16f), 0.04f);
        const float cz = __fdiv_rn(__fadd_rn(dz, 0.16f), 0.04f);
        int vx = (int)rintf(cx); vx = vx < 0 ? 0 : (vx > 8 ? 8 : vx);
        int vy = (int)rintf(cy); vy = vy < 0 ? 0 : (vy > 8 ? 8 : vy);
        int vz = (int)rintf(cz); vz = vz < 0 ? 0 : (vz > 8 ? 8 : vz);
        __hip_atomic_fetch_add(&bins[(vx*NG1 + vy)*NG1 + vz], pv,
                               __ATOMIC_RELAXED, __HIP_MEMORY_SCOPE_WORKGROUP);
      }
    }
  }
  for (int off = 32; off; off >>= 1) {
    fx += __shfl_xor(fx, off); fy += __shfl_xor(fy, off); fz += __shfl_xor(fz, off);
  }
  if (lane == 0) {
    float* f = out + (size_t)((size_t)b*NL0 + l0)*3;
    f[0] = fx; f[1] = fy; f[2] = fz;
  }
}

extern "C" void kernel_launch(void* const* d_in, const int* in_sizes, int n_in,
                              void* d_out, int out_size, void* d_ws, size_t ws_size,
                              hipStream_t stream) {
  const float* x0   = (const float*)d_in[0];
  const float* x1   = (const float*)d_in[1];
  const float* pos0 = (const float*)d_in[2];
  const float* pos1 = (const float*)d_in[3];
  const void*  pad  = d_in[4];
  float* out = (float*)d_out;
  (void)in_sizes; (void)n_in; (void)out_size; (void)d_ws; (void)ws_size;
  hipLaunchKernelGGL(fine_match_kernel, dim3(NB*NL0/QPB), dim3(TPB), 0, stream,
                     x0, x1, pos0, pos1, pad, out);
}

// Round 8
// 30.921 us; speedup vs baseline: 1.2601x; 1.1094x over previous
//
#include <hip/hip_runtime.h>
#include <stdint.h>

#define NB    4
#define NL0   2048
#define NL1   2048
#define NC    64
#define KMAX  128
#define CAP   256
#define NG1   9
#define NBINS 729
#define FLOWN (NB*NL0*3)
#define QPB   16     // 2 queries per wave, 8 waves
#define TPB   512

__global__ __launch_bounds__(TPB, 4) void fine_match_kernel(
    const float* __restrict__ x0, const float* __restrict__ x1,
    const float* __restrict__ pos0, const float* __restrict__ pos1,
    const void* __restrict__ padraw, float* __restrict__ out)
{
  __shared__ float          s_pos[NL1*3];     // 24 KB AoS; stride-3 word reads conflict-free
  __shared__ float          s_x0[QPB*NC];     // 4 KB
  __shared__ float          s_p0[QPB][3];
  __shared__ unsigned short s_jj[QPB][CAP];   // 8 KB
  __shared__ float          s_corr[QPB][CAP]; // 16 KB, lane-private slots

  const int t = threadIdx.x;
  const int bid = blockIdx.x;
  const int b = bid >> 7;                 // 128 blocks per batch
  const int l0base = (bid & 127) * QPB;

  // ---- pad width detection: 4-byte (i32 / f32 bool) vs packed byte ----
  int wide;
  {
    const uint32_t* pi = (const uint32_t*)padraw;
    int ok4 = 1;
    for (int i = t; i < (NB*NL1)/4; i += TPB) {
      const uint32_t v = pi[i];
      ok4 &= (int)((v <= 1u) | (v == 0x3F800000u));
    }
    wide = __syncthreads_and(ok4);        // block-uniform
  }

  // ---- staging: pos1 raw float4 copy, x0 rows, pos0; zero flow_dist region ----
  {
    const float4* src = (const float4*)(pos1 + (size_t)b*NL1*3);
    float4* dst = (float4*)s_pos;
    for (int i = t; i < NL1*3/4; i += TPB) dst[i] = src[i];   // 3 iters
  }
  for (int i = t; i < QPB*NC; i += TPB)                       // 2 iters
    s_x0[i] = x0[(size_t)(b*NL0 + l0base)*NC + i];
  if (t < QPB*3) {
    const int q = t/3, c = t - q*3;
    s_p0[q][c] = pos0[(b*NL0 + l0base + q)*3 + c];
  }
  {
    float4 z4; z4.x = z4.y = z4.z = z4.w = 0.0f;
    float4* bz = (float4*)(out + FLOWN + (size_t)(b*NL0 + l0base)*NBINS);
    for (int i = t; i < QPB*NBINS/4; i += TPB) bz[i] = z4;    // 2916 float4s
  }
  __syncthreads();   // LDS visible + zero-stores drained before any atomics

  const int wv = t >> 6, lane = t & 63;
  const int q0 = wv*2, q1 = wv*2 + 1;
  const float ax = s_p0[q0][0], ay = s_p0[q0][1], az = s_p0[q0][2];
  const float bx = s_p0[q1][0], by = s_p0[q1][1], bz = s_p0[q1][2];

  // ---- phase 1: one LDS point read feeds BOTH queries' radius tests ----
  int cnt0 = 0, cnt1 = 0;
  for (int base = 0; base < NL1; base += 64) {
    const int j = base + lane;
    const float px = s_pos[j*3+0], py = s_pos[j*3+1], pz = s_pos[j*3+2];
    const float dxa = __fsub_rn(px, ax), dya = __fsub_rn(py, ay), dza = __fsub_rn(pz, az);
    const float dxb = __fsub_rn(px, bx), dyb = __fsub_rn(py, by), dzb = __fsub_rn(pz, bz);
    const float d2a = __fadd_rn(__fadd_rn(__fmul_rn(dxa,dxa), __fmul_rn(dya,dya)), __fmul_rn(dza,dza));
    const float d2b = __fadd_rn(__fadd_rn(__fmul_rn(dxb,dxb), __fmul_rn(dyb,dyb)), __fmul_rn(dzb,dzb));
    const bool oka = d2a < 0.0324f;            // strict <, matches reference
    const bool okb = d2b < 0.0324f;
    const uint64_t m0 = __ballot(oka);
    const uint64_t m1 = __ballot(okb);
    const uint64_t lm = (1ull << lane) - 1ull;
    if (oka) {
      const int pos = cnt0 + (int)__popcll(m0 & lm);
      if (pos < CAP) s_jj[q0][pos] = (unsigned short)j;
    }
    if (okb) {
      const int pos = cnt1 + (int)__popcll(m1 & lm);
      if (pos < CAP) s_jj[q1][pos] = (unsigned short)j;
    }
    cnt0 += (int)__popcll(m0);
    cnt1 += (int)__popcll(m1);
  }
  if (cnt0 > CAP) cnt0 = CAP;
  if (cnt1 > CAP) cnt1 = CAP;
  // no barrier: s_jj / s_corr are wave-private from here on

  // ---- phases 2-4 per owned query (unrolled: all LDS indices static) ----
  #pragma unroll
  for (int u = 0; u < 2; ++u) {
    const int qi  = (u == 0) ? q0 : q1;
    const int cnt = (u == 0) ? cnt0 : cnt1;
    const int l0  = l0base + qi;
    const float p0x = (u == 0) ? ax : bx;
    const float p0y = (u == 0) ? ay : by;
    const float p0z = (u == 0) ? az : bz;

    // phase 2: pad filter, rare exact rank-select, correlation
    const bool over = (cnt > KMAX);
    for (int s = 0; s < 4; ++s) {
      if (64*s >= cnt) break;                  // wave-uniform early exit
      const int i = lane + 64*s;
      if (i < cnt) {
        float c = -1e30f;
        const int j = (int)s_jj[qi][i];
        bool k;
        if (wide) k = (((const uint32_t*)padraw)[b*NL1 + j] == 0u);
        else      k = (((const uint8_t*)padraw)[b*NL1 + j] == 0);
        if (over && k) {  // rank over ALL in-radius candidates, tie-break by list order
          const float dx = __fsub_rn(s_pos[j*3+0], p0x);
          const float dy = __fsub_rn(s_pos[j*3+1], p0y);
          const float dz = __fsub_rn(s_pos[j*3+2], p0z);
          const float di = __fadd_rn(__fadd_rn(__fmul_rn(dx,dx), __fmul_rn(dy,dy)), __fmul_rn(dz,dz));
          int rank = 0;
          for (int m2 = 0; m2 < cnt; ++m2) {
            const int jm = (int)s_jj[qi][m2];
            const float ex = __fsub_rn(s_pos[jm*3+0], p0x);
            const float ey = __fsub_rn(s_pos[jm*3+1], p0y);
            const float ez = __fsub_rn(s_pos[jm*3+2], p0z);
            const float dm = __fadd_rn(__fadd_rn(__fmul_rn(ex,ex), __fmul_rn(ey,ey)), __fmul_rn(ez,ez));
            rank += (dm < di || (dm == di && m2 < i)) ? 1 : 0;
          }
          if (rank >= KMAX) k = false;
        }
        if (k) {
          const float* xr = x1 + ((size_t)b*NL1 + j)*NC;
          float acc = 0.0f;
          #pragma unroll
          for (int cc = 0; cc < NC; cc += 4) {
            const float4 v = *(const float4*)(xr + cc);
            const float4 q = *(const float4*)(&s_x0[qi*NC + cc]);  // broadcast
            acc += q.x*v.x + q.y*v.y + q.z*v.z + q.w*v.w;
          }
          c = acc * 0.125f;   // / sqrt(64)
        }
        s_corr[qi][i] = c;
      }
    }

    // phase 3: wave softmax stats (max, sum)
    float mx = -1e30f;
    for (int s = 0; s < 4; ++s) {
      if (64*s >= cnt) break;
      const int i = lane + 64*s;
      if (i < cnt) { const float c = s_corr[qi][i]; if (c > mx) mx = c; }
    }
    for (int off = 32; off; off >>= 1) { const float o = __shfl_xor(mx, off); if (o > mx) mx = o; }
    float sum = 0.0f;
    for (int s = 0; s < 4; ++s) {
      if (64*s >= cnt) break;
      const int i = lane + 64*s;
      if (i < cnt) { const float c = s_corr[qi][i]; if (c > -1e30f) sum += expf(c - mx); }
    }
    for (int off = 32; off; off >>= 1) sum += __shfl_xor(sum, off);
    const float inv = (sum > 0.0f) ? (1.0f / sum) : 0.0f;

    // phase 4: flow + voxel scatter (workgroup-scope atomics into local L2)
    float* bins = out + FLOWN + (size_t)((size_t)b*NL0 + l0)*NBINS;
    float fx = 0.0f, fy = 0.0f, fz = 0.0f;
    for (int s = 0; s < 4; ++s) {
      if (64*s >= cnt) break;
      const int i = lane + 64*s;
      if (i < cnt) {
        const float c = s_corr[qi][i];
        if (c > -1e30f) {
          const float pv = expf(c - mx) * inv;   // identical to phase-3 term * inv
          const int j = (int)s_jj[qi][i];
          const float dx = __fsub_rn(s_pos[j*3+0], p0x);
          const float dy = __fsub_rn(s_pos[j*3+1], p0y);
          const float dz = __fsub_rn(s_pos[j*3+2], p0z);
          fx += pv*dx; fy += pv*dy; fz += pv*dz;
          const float cx = __fdiv_rn(__fadd_rn(dx, 0.16f), 0.04f);
          const float cy = __fdiv_rn(__fadd_rn(dy, 0.16f), 0.04f);
          const float cz = __fdiv_rn(__fadd_rn(dz, 0.16f), 0.04f);
          int vx = (int)rintf(cx); vx = vx < 0 ? 0 : (vx > 8 ? 8 : vx);
          int vy = (int)rintf(cy); vy = vy < 0 ? 0 : (vy > 8 ? 8 : vy);
          int vz = (int)rintf(cz); vz = vz < 0 ? 0 : (vz > 8 ? 8 : vz);
          __hip_atomic_fetch_add(&bins[(vx*NG1 + vy)*NG1 + vz], pv,
                                 __ATOMIC_RELAXED, __HIP_MEMORY_SCOPE_WORKGROUP);
        }
      }
    }
    for (int off = 32; off; off >>= 1) {
      fx += __shfl_xor(fx, off); fy += __shfl_xor(fy, off); fz += __shfl_xor(fz, off);
    }
    if (lane == 0) {
      float* f = out + (size_t)((size_t)b*NL0 + l0)*3;
      f[0] = fx; f[1] = fy; f[2] = fz;
    }
  }
}

extern "C" void kernel_launch(void* const* d_in, const int* in_sizes, int n_in,
                              void* d_out, int out_size, void* d_ws, size_t ws_size,
                              hipStream_t stream) {
  const float* x0   = (const float*)d_in[0];
  const float* x1   = (const float*)d_in[1];
  const float* pos0 = (const float*)d_in[2];
  const float* pos1 = (const float*)d_in[3];
  const void*  pad  = d_in[4];
  float* out = (float*)d_out;
  (void)in_sizes; (void)n_in; (void)out_size; (void)d_ws; (void)ws_size;
  hipLaunchKernelGGL(fine_match_kernel, dim3(NB*NL0/QPB), dim3(TPB), 0, stream,
                     x0, x1, pos0, pos1, pad, out);
}